// Round 1
// baseline (70.976 us; speedup 1.0000x reference)
//
#include <hip/hip_runtime.h>
#include <math.h>

#define EPSF 1e-6f
#define NB 4
#define NR 16384
#define NS 48
#define NSEG 47
#define CS 8
#define NCH (NS / CS)
#define NRAYS (NB * NR)

__device__ __forceinline__ unsigned int f2ord(float f) {
    unsigned int u = __float_as_uint(f);
    return (u & 0x80000000u) ? ~u : (u | 0x80000000u);
}
__device__ __forceinline__ float ord2f(unsigned int v) {
    return __uint_as_float((v & 0x80000000u) ? (v ^ 0x80000000u) : ~v);
}
__device__ __forceinline__ float softplus_f(float x) {
    // jax.nn.softplus = logaddexp(x, 0) = max(x,0) + log1p(exp(-|x|))
    return fmaxf(x, 0.0f) + log1pf(expf(-fabsf(x)));
}

__global__ void init_mm(unsigned int* mm) {
    mm[0] = 0xFFFFFFFFu;  // running-min ordinal
    mm[1] = 0u;           // running-max ordinal
}

__global__ __launch_bounds__(256) void minmax_kernel(const float4* __restrict__ z,
                                                     unsigned int* mm) {
    const int n4 = (NRAYS * NS) / 4;
    float lmin = INFINITY, lmax = -INFINITY;
    for (int i = blockIdx.x * blockDim.x + threadIdx.x; i < n4;
         i += gridDim.x * blockDim.x) {
        float4 v = z[i];
        lmin = fminf(lmin, fminf(fminf(v.x, v.y), fminf(v.z, v.w)));
        lmax = fmaxf(lmax, fmaxf(fmaxf(v.x, v.y), fmaxf(v.z, v.w)));
    }
#pragma unroll
    for (int off = 32; off > 0; off >>= 1) {
        lmin = fminf(lmin, __shfl_down(lmin, off));
        lmax = fmaxf(lmax, __shfl_down(lmax, off));
    }
    __shared__ float smin[4], smax[4];
    int wid = threadIdx.x >> 6;
    if ((threadIdx.x & 63) == 0) { smin[wid] = lmin; smax[wid] = lmax; }
    __syncthreads();
    if (threadIdx.x == 0) {
        float m = fminf(fminf(smin[0], smin[1]), fminf(smin[2], smin[3]));
        float M = fmaxf(fmaxf(smax[0], smax[1]), fmaxf(smax[2], smax[3]));
        atomicMin(&mm[0], f2ord(m));
        atomicMax(&mm[1], f2ord(M));
    }
}

__global__ __launch_bounds__(256) void march_kernel(
    const float* __restrict__ colors, const float* __restrict__ densities,
    const float* __restrict__ depths, const float* __restrict__ semantics,
    const int* __restrict__ levels, const unsigned int* __restrict__ mm,
    float* __restrict__ out) {
    const int ray = blockIdx.x * blockDim.x + threadIdx.x;  // 0..NRAYS-1
    const int b = ray >> 14;                                // ray / NR
    const int lv = levels[b];
    const float dmin = ord2f(mm[0]);
    const float dmax = ord2f(mm[1]);

    const float4* c4 = (const float4*)(colors + (size_t)ray * (NS * 3));
    const float4* d4 = (const float4*)(densities + (size_t)ray * NS);
    const float4* z4 = (const float4*)(depths + (size_t)ray * NS);
    const float4* s4 = (const float4*)(semantics + (size_t)ray * (NS * 4));

    float* wout = out + (size_t)(NB * NR * 8) + (size_t)ray * NSEG;

    float T = 1.0f;
    float acc_r = 0.f, acc_g = 0.f, acc_b = 0.f, acc_d = 0.f;
    float acc_s0 = 0.f, acc_s1 = 0.f, acc_s2 = 0.f, acc_s3 = 0.f;

    // carried previous sample
    float pc0 = 0.f, pc1 = 0.f, pc2 = 0.f, pdn = 0.f, pz = 0.f;
    float ps0 = 0.f, ps1 = 0.f, ps2 = 0.f, ps3 = 0.f;

    for (int ch = 0; ch < NCH; ++ch) {
        float cf[CS * 3];
        {
            const float4* p = c4 + ch * ((CS * 3) / 4);
#pragma unroll
            for (int k = 0; k < (CS * 3) / 4; ++k) {
                float4 t = p[k];
                cf[4 * k + 0] = t.x; cf[4 * k + 1] = t.y;
                cf[4 * k + 2] = t.z; cf[4 * k + 3] = t.w;
            }
        }
        float sf[CS * 4];
        {
            const float4* p = s4 + ch * CS;
#pragma unroll
            for (int k = 0; k < CS; ++k) {
                float4 t = p[k];
                sf[4 * k + 0] = t.x; sf[4 * k + 1] = t.y;
                sf[4 * k + 2] = t.z; sf[4 * k + 3] = t.w;
            }
        }
        float df[CS];
        {
            const float4* p = d4 + ch * (CS / 4);
#pragma unroll
            for (int k = 0; k < CS / 4; ++k) {
                float4 t = p[k];
                df[4 * k + 0] = t.x; df[4 * k + 1] = t.y;
                df[4 * k + 2] = t.z; df[4 * k + 3] = t.w;
            }
        }
        float zf[CS];
        {
            const float4* p = z4 + ch * (CS / 4);
#pragma unroll
            for (int k = 0; k < CS / 4; ++k) {
                float4 t = p[k];
                zf[4 * k + 0] = t.x; zf[4 * k + 1] = t.y;
                zf[4 * k + 2] = t.z; zf[4 * k + 3] = t.w;
            }
        }

#pragma unroll
        for (int s = 0; s < CS; ++s) {
            float c0 = cf[s * 3 + 0], c1 = cf[s * 3 + 1], c2 = cf[s * 3 + 2];
            float dn = df[s], z = zf[s];
            float m0 = sf[s * 4 + 0], m1 = sf[s * 4 + 1];
            float m2 = sf[s * 4 + 2], m3 = sf[s * 4 + 3];

            if (!(ch == 0 && s == 0)) {
                float delta = z - pz;
                float cm0 = (pc0 + c0) * 0.5f;
                float cm1 = (pc1 + c1) * 0.5f;
                float cm2 = (pc2 + c2) * 0.5f;
                float dnm = (pdn + dn) * 0.5f;
                float zm = (pz + z) * 0.5f;
                float sm0 = (ps0 + m0) * 0.5f;
                float sm1 = (ps1 + m1) * 0.5f;
                float sm2 = (ps2 + m2) * 0.5f;
                float sm3 = (ps3 + m3) * 0.5f;

                float sp = softplus_f(dnm);
                float alpha = 1.0f - expf(-sp * delta);

                float factor, o0, o1, o2, o3;
                if (lv == 1) {
                    factor = 1.0f - sm0;
                    float inv = 1.0f / (sm1 + sm2 + sm3 + EPSF);
                    o0 = 0.0f;
                    o1 = (sm1 + EPSF) * inv;
                    o2 = (sm2 + EPSF) * inv;
                    o3 = (sm3 + EPSF) * inv;
                } else if (lv == 2) {
                    factor = 1.0f - sm0 - sm3;
                    float inv = 1.0f / (sm1 + sm2 + EPSF);
                    o0 = 0.0f;
                    o1 = (sm1 + EPSF) * inv;
                    o2 = (sm2 + EPSF) * inv;
                    o3 = 0.0f;
                } else {
                    factor = 1.0f;
                    o0 = sm0; o1 = sm1; o2 = sm2; o3 = sm3;
                }

                alpha *= factor;
                float w = alpha * T;
                T *= (1.0f - alpha + 1e-10f);

                wout[ch * CS + s - 1] = w;

                acc_r += w * cm0;
                acc_g += w * cm1;
                acc_b += w * cm2;
                acc_d += w * zm;
                acc_s0 += w * o0;
                acc_s1 += w * o1;
                acc_s2 += w * o2;
                acc_s3 += w * o3;
            }
            pc0 = c0; pc1 = c1; pc2 = c2;
            pdn = dn; pz = z;
            ps0 = m0; ps1 = m1; ps2 = m2; ps3 = m3;
        }
    }

    // composite_depth: NaN -> inf, then clip to [global min, global max]
    if (isnan(acc_d)) acc_d = INFINITY;
    acc_d = fminf(fmaxf(acc_d, dmin), dmax);

    out[ray * 3 + 0] = acc_r;
    out[ray * 3 + 1] = acc_g;
    out[ray * 3 + 2] = acc_b;
    out[NB * NR * 3 + ray] = acc_d;
    out[NB * NR * 4 + ray * 4 + 0] = acc_s0;
    out[NB * NR * 4 + ray * 4 + 1] = acc_s1;
    out[NB * NR * 4 + ray * 4 + 2] = acc_s2;
    out[NB * NR * 4 + ray * 4 + 3] = acc_s3;
}

extern "C" void kernel_launch(void* const* d_in, const int* in_sizes, int n_in,
                              void* d_out, int out_size, void* d_ws, size_t ws_size,
                              hipStream_t stream) {
    const float* colors = (const float*)d_in[0];
    const float* densities = (const float*)d_in[1];
    const float* depths = (const float*)d_in[2];
    const float* semantics = (const float*)d_in[3];
    const int* levels = (const int*)d_in[4];
    float* out = (float*)d_out;
    unsigned int* mm = (unsigned int*)d_ws;

    init_mm<<<1, 1, 0, stream>>>(mm);
    minmax_kernel<<<512, 256, 0, stream>>>((const float4*)depths, mm);
    march_kernel<<<NRAYS / 256, 256, 0, stream>>>(colors, densities, depths,
                                                  semantics, levels, mm, out);
}

// Round 2
// 49.006 us; speedup vs baseline: 1.4483x; 1.4483x over previous
//
#include <hip/hip_runtime.h>
#include <math.h>

#define EPSF 1e-6f
#define NB 4
#define NR 16384
#define NS 48
#define NSEG 47
#define NRAYS (NB * NR)
// 8 lanes cooperate on one ray; each lane owns 6 samples (lane 7: 5 segments).
#define KL 8
#define SPL 6

__device__ __forceinline__ unsigned int f2ord(float f) {
    unsigned int u = __float_as_uint(f);
    return (u & 0x80000000u) ? ~u : (u | 0x80000000u);
}
__device__ __forceinline__ float ord2f(unsigned int v) {
    return __uint_as_float((v & 0x80000000u) ? (v ^ 0x80000000u) : ~v);
}
__device__ __forceinline__ float softplus_f(float x) {
    return fmaxf(x, 0.0f) + log1pf(expf(-fabsf(x)));
}

__global__ void init_mm(unsigned int* mm) {
    mm[0] = 0xFFFFFFFFu;
    mm[1] = 0u;
}

__global__ __launch_bounds__(256) void minmax_kernel(const float4* __restrict__ z,
                                                     unsigned int* mm) {
    const int n4 = (NRAYS * NS) / 4;
    float lmin = INFINITY, lmax = -INFINITY;
    for (int i = blockIdx.x * blockDim.x + threadIdx.x; i < n4;
         i += gridDim.x * blockDim.x) {
        float4 v = z[i];
        lmin = fminf(lmin, fminf(fminf(v.x, v.y), fminf(v.z, v.w)));
        lmax = fmaxf(lmax, fmaxf(fmaxf(v.x, v.y), fmaxf(v.z, v.w)));
    }
#pragma unroll
    for (int off = 32; off > 0; off >>= 1) {
        lmin = fminf(lmin, __shfl_down(lmin, off));
        lmax = fmaxf(lmax, __shfl_down(lmax, off));
    }
    __shared__ float smin[4], smax[4];
    int wid = threadIdx.x >> 6;
    if ((threadIdx.x & 63) == 0) { smin[wid] = lmin; smax[wid] = lmax; }
    __syncthreads();
    if (threadIdx.x == 0) {
        float m = fminf(fminf(smin[0], smin[1]), fminf(smin[2], smin[3]));
        float M = fmaxf(fmaxf(smax[0], smax[1]), fmaxf(smax[2], smax[3]));
        atomicMin(&mm[0], f2ord(m));
        atomicMax(&mm[1], f2ord(M));
    }
}

__global__ __launch_bounds__(256) void march_kernel(
    const float* __restrict__ colors, const float* __restrict__ densities,
    const float* __restrict__ depths, const float* __restrict__ semantics,
    const int* __restrict__ levels, const unsigned int* __restrict__ mm,
    float* __restrict__ out) {
    const int tid = blockIdx.x * blockDim.x + threadIdx.x;
    const int ray = tid >> 3;      // 8 lanes per ray
    const int t = tid & 7;         // lane-in-group: owns samples 6t..6t+5
    const int b = ray >> 14;
    const int lv = levels[b];

    // ---- vectorized loads of this lane's 6 samples ----
    const float2* cp = (const float2*)colors + (size_t)ray * 72 + t * 9;
    const float2* dp = (const float2*)densities + (size_t)ray * 24 + t * 3;
    const float2* zp = (const float2*)depths + (size_t)ray * 24 + t * 3;
    const float4* sp = (const float4*)semantics + (size_t)ray * 48 + t * 6;

    float C0[7], C1[7], C2[7], DN[7], Z[7], S0[7], S1[7], S2[7], S3[7];

    float2 q0 = cp[0], q1 = cp[1], q2 = cp[2], q3 = cp[3], q4 = cp[4];
    float2 q5 = cp[5], q6 = cp[6], q7 = cp[7], q8 = cp[8];
    C0[0] = q0.x; C1[0] = q0.y; C2[0] = q1.x;
    C0[1] = q1.y; C1[1] = q2.x; C2[1] = q2.y;
    C0[2] = q3.x; C1[2] = q3.y; C2[2] = q4.x;
    C0[3] = q4.y; C1[3] = q5.x; C2[3] = q5.y;
    C0[4] = q6.x; C1[4] = q6.y; C2[4] = q7.x;
    C0[5] = q7.y; C1[5] = q8.x; C2[5] = q8.y;

    float2 r0 = dp[0], r1 = dp[1], r2 = dp[2];
    DN[0] = r0.x; DN[1] = r0.y; DN[2] = r1.x;
    DN[3] = r1.y; DN[4] = r2.x; DN[5] = r2.y;

    float2 e0 = zp[0], e1 = zp[1], e2 = zp[2];
    Z[0] = e0.x; Z[1] = e0.y; Z[2] = e1.x;
    Z[3] = e1.y; Z[4] = e2.x; Z[5] = e2.y;

#pragma unroll
    for (int j = 0; j < SPL; ++j) {
        float4 u = sp[j];
        S0[j] = u.x; S1[j] = u.y; S2[j] = u.z; S3[j] = u.w;
    }

    // boundary sample 6t+6 == neighbor lane's sample 0 (lane 7 never uses it)
    C0[6] = __shfl_down(C0[0], 1, KL);
    C1[6] = __shfl_down(C1[0], 1, KL);
    C2[6] = __shfl_down(C2[0], 1, KL);
    DN[6] = __shfl_down(DN[0], 1, KL);
    Z[6]  = __shfl_down(Z[0], 1, KL);
    S0[6] = __shfl_down(S0[0], 1, KL);
    S1[6] = __shfl_down(S1[0], 1, KL);
    S2[6] = __shfl_down(S2[0], 1, KL);
    S3[6] = __shfl_down(S3[0], 1, KL);

    // ---- local pass: T starts at 1 within this lane's chunk ----
    float T = 1.0f;
    float wl[SPL];
    float acc_r = 0.f, acc_g = 0.f, acc_b = 0.f, acc_d = 0.f;
    float acc_s0 = 0.f, acc_s1 = 0.f, acc_s2 = 0.f, acc_s3 = 0.f;

#pragma unroll
    for (int j = 0; j < SPL; ++j) {
        wl[j] = 0.0f;
        if (j < 5 || t < 7) {   // lane 7 only has 5 segments
            float delta = Z[j + 1] - Z[j];
            float cm0 = (C0[j] + C0[j + 1]) * 0.5f;
            float cm1 = (C1[j] + C1[j + 1]) * 0.5f;
            float cm2 = (C2[j] + C2[j + 1]) * 0.5f;
            float dnm = (DN[j] + DN[j + 1]) * 0.5f;
            float zm  = (Z[j] + Z[j + 1]) * 0.5f;
            float sm0 = (S0[j] + S0[j + 1]) * 0.5f;
            float sm1 = (S1[j] + S1[j + 1]) * 0.5f;
            float sm2 = (S2[j] + S2[j + 1]) * 0.5f;
            float sm3 = (S3[j] + S3[j + 1]) * 0.5f;

            float sp_ = softplus_f(dnm);
            float alpha = 1.0f - expf(-sp_ * delta);

            float factor, o0, o1, o2, o3;
            if (lv == 1) {
                factor = 1.0f - sm0;
                float inv = 1.0f / (sm1 + sm2 + sm3 + EPSF);
                o0 = 0.0f;
                o1 = (sm1 + EPSF) * inv;
                o2 = (sm2 + EPSF) * inv;
                o3 = (sm3 + EPSF) * inv;
            } else if (lv == 2) {
                factor = 1.0f - sm0 - sm3;
                float inv = 1.0f / (sm1 + sm2 + EPSF);
                o0 = 0.0f;
                o1 = (sm1 + EPSF) * inv;
                o2 = (sm2 + EPSF) * inv;
                o3 = 0.0f;
            } else {
                factor = 1.0f;
                o0 = sm0; o1 = sm1; o2 = sm2; o3 = sm3;
            }

            alpha *= factor;
            float w = alpha * T;
            T *= (1.0f - alpha + 1e-10f);
            wl[j] = w;

            acc_r += w * cm0;
            acc_g += w * cm1;
            acc_b += w * cm2;
            acc_d += w * zm;
            acc_s0 += w * o0;
            acc_s1 += w * o1;
            acc_s2 += w * o2;
            acc_s3 += w * o3;
        }
    }

    // ---- inclusive product scan of local transmittance across the 8 lanes ----
    float p = T;
#pragma unroll
    for (int off = 1; off < KL; off <<= 1) {
        float u = __shfl_up(p, off, KL);
        if (t >= off) p *= u;
    }
    float Tstart = __shfl_up(p, 1, KL);
    if (t == 0) Tstart = 1.0f;

    // rescale local results: w_global = Tstart * w_local
    acc_r *= Tstart; acc_g *= Tstart; acc_b *= Tstart; acc_d *= Tstart;
    acc_s0 *= Tstart; acc_s1 *= Tstart; acc_s2 *= Tstart; acc_s3 *= Tstart;

    // write weights (lane t covers segments 6t..6t+5; lane 7 only 5)
    float* wout = out + (size_t)(NRAYS * 8) + (size_t)ray * NSEG + t * SPL;
#pragma unroll
    for (int j = 0; j < SPL; ++j) {
        if (j < 5 || t < 7) wout[j] = wl[j] * Tstart;
    }

    // ---- reduce the 8 partial composites across the group ----
#pragma unroll
    for (int off = KL / 2; off > 0; off >>= 1) {
        acc_r += __shfl_down(acc_r, off, KL);
        acc_g += __shfl_down(acc_g, off, KL);
        acc_b += __shfl_down(acc_b, off, KL);
        acc_d += __shfl_down(acc_d, off, KL);
        acc_s0 += __shfl_down(acc_s0, off, KL);
        acc_s1 += __shfl_down(acc_s1, off, KL);
        acc_s2 += __shfl_down(acc_s2, off, KL);
        acc_s3 += __shfl_down(acc_s3, off, KL);
    }

    if (t == 0) {
        const float dmin = ord2f(mm[0]);
        const float dmax = ord2f(mm[1]);
        if (isnan(acc_d)) acc_d = INFINITY;
        acc_d = fminf(fmaxf(acc_d, dmin), dmax);

        out[ray * 3 + 0] = acc_r;
        out[ray * 3 + 1] = acc_g;
        out[ray * 3 + 2] = acc_b;
        out[NRAYS * 3 + ray] = acc_d;
        out[NRAYS * 4 + ray * 4 + 0] = acc_s0;
        out[NRAYS * 4 + ray * 4 + 1] = acc_s1;
        out[NRAYS * 4 + ray * 4 + 2] = acc_s2;
        out[NRAYS * 4 + ray * 4 + 3] = acc_s3;
    }
}

extern "C" void kernel_launch(void* const* d_in, const int* in_sizes, int n_in,
                              void* d_out, int out_size, void* d_ws, size_t ws_size,
                              hipStream_t stream) {
    const float* colors = (const float*)d_in[0];
    const float* densities = (const float*)d_in[1];
    const float* depths = (const float*)d_in[2];
    const float* semantics = (const float*)d_in[3];
    const int* levels = (const int*)d_in[4];
    float* out = (float*)d_out;
    unsigned int* mm = (unsigned int*)d_ws;

    init_mm<<<1, 1, 0, stream>>>(mm);
    minmax_kernel<<<512, 256, 0, stream>>>((const float4*)depths, mm);
    march_kernel<<<(NRAYS * KL) / 256, 256, 0, stream>>>(
        colors, densities, depths, semantics, levels, mm, out);
}